// Round 4
// baseline (121.224 us; speedup 1.0000x reference)
//
#include <hip/hip_runtime.h>

// Problem constants (from reference)
#define B_      32
#define I_      16
#define C_      128
#define T_      2048
#define D_      8
#define OUT_CH_ 128          // I_ * D_
#define MAX_NORM_ 1.0f

// Each block: one (b, i) pair, one tile of 1024 t (512 threads x float2).
// Grid = (T/1024, I, B) = (2, 16, 32) = 1024 blocks.
// 4 blocks/CU x 8 waves = 32 waves/CU (8/SIMD, max occupancy) for read MLP.
__global__ __launch_bounds__(512, 8)
void DepthwiseSpatialConvROCm_kernel(const float* __restrict__ x,
                                     const float* __restrict__ weight,
                                     float* __restrict__ out)
{
    __shared__ __align__(16) float w_lds[C_][D_];   // [c][d], max-norm-scaled, 4 KB
    __shared__ float s_scale[D_];

    const int tid = threadIdx.x;
    const int t0  = blockIdx.x * 1024;
    const int i   = blockIdx.y;
    const int b   = blockIdx.z;

    // --- stage weight slice for this i: weight[(i*8 + d)*128 + c] ---
    // element e = tid*4 + k  ->  d = e/128 = tid>>5,  c = e%128   (threads 0..255)
    const int wd = tid >> 5;
    const int wc = (tid * 4) & (C_ - 1);
    if (tid < 256) {
        const float4 wv = *reinterpret_cast<const float4*>(
            weight + (size_t)i * (D_ * C_) + tid * 4);
        w_lds[wc + 0][wd] = wv.x;
        w_lds[wc + 1][wd] = wv.y;
        w_lds[wc + 2][wd] = wv.z;
        w_lds[wc + 3][wd] = wv.w;
    }
    __syncthreads();

    // --- per-row L2 norm + max-norm scale (threads 0..127; 16 lanes per d) ---
    if (tid < 128) {
        const int d = tid >> 4;
        const int g = tid & 15;
        float s = 0.f;
        #pragma unroll
        for (int k = 0; k < 8; ++k) {
            const float v = w_lds[g * 8 + k][d];
            s = fmaf(v, v, s);
        }
        s += __shfl_xor(s, 1);
        s += __shfl_xor(s, 2);
        s += __shfl_xor(s, 4);
        s += __shfl_xor(s, 8);
        if (g == 0) {
            const float norm = sqrtf(s);
            s_scale[d] = fminf(1.0f, MAX_NORM_ / fmaxf(norm, 1e-12f));
        }
    }
    __syncthreads();
    if (tid < 256) {
        const float sc = s_scale[wd];
        w_lds[wc + 0][wd] *= sc;
        w_lds[wc + 1][wd] *= sc;
        w_lds[wc + 2][wd] *= sc;
        w_lds[wc + 3][wd] *= sc;
    }
    __syncthreads();

    // --- main loop: acc[d] += x[b,i,c,t0+tid*2 .. +1] * w[c][d] ---
    const float* xp = x + ((size_t)(b * I_ + i) * C_) * T_ + t0 + tid * 2;

    float2 acc[D_];
    #pragma unroll
    for (int d = 0; d < D_; ++d) acc[d] = make_float2(0.f, 0.f);

    #pragma unroll 8
    for (int c = 0; c < C_; ++c) {
        const float2 xv = *reinterpret_cast<const float2*>(xp + (size_t)c * T_);
        #pragma unroll
        for (int d = 0; d < D_; ++d) {
            const float w = w_lds[c][d];   // same-address broadcast
            acc[d].x = fmaf(xv.x, w, acc[d].x);
            acc[d].y = fmaf(xv.y, w, acc[d].y);
        }
    }

    // --- store: out[b, i*8+d, 0, t] ---
    float* op = out + ((size_t)(b * OUT_CH_ + i * D_)) * T_ + t0 + tid * 2;
    #pragma unroll
    for (int d = 0; d < D_; ++d) {
        *reinterpret_cast<float2*>(op + (size_t)d * T_) = acc[d];
    }
}

extern "C" void kernel_launch(void* const* d_in, const int* in_sizes, int n_in,
                              void* d_out, int out_size, void* d_ws, size_t ws_size,
                              hipStream_t stream)
{
    const float* x = (const float*)d_in[0];
    const float* w = (const float*)d_in[1];
    float* out     = (float*)d_out;

    dim3 grid(T_ / 1024, I_, B_);   // (2, 16, 32)
    DepthwiseSpatialConvROCm_kernel<<<grid, 512, 0, stream>>>(x, w, out);
}

// Round 5
// 92.106 us; speedup vs baseline: 1.3161x; 1.3161x over previous
//
#include <hip/hip_runtime.h>

// Problem constants (from reference)
#define B_      32
#define I_      16
#define C_      128
#define T_      2048
#define D_      8
#define OUT_CH_ 128          // I_ * D_
#define MAX_NORM_ 1.0f

typedef float f32x4 __attribute__((ext_vector_type(4)));

// Each block: one (b, i) pair, FULL T=2048 (512 threads x float4).
// Grid = (I, B) = (16, 32) = 512 blocks, 2 blocks/CU, 16 waves/CU.
// x is streamed once with NO reuse -> non-temporal loads/stores to avoid
// L2/LLC allocation churn (512 MiB stream vs 256 MiB LLC).
__global__ __launch_bounds__(512)
void DepthwiseSpatialConvROCm_kernel(const float* __restrict__ x,
                                     const float* __restrict__ weight,
                                     float* __restrict__ out)
{
    __shared__ __align__(16) float w_lds[C_][D_];   // [c][d], max-norm-scaled, 4 KB
    __shared__ float s_scale[D_];

    const int tid = threadIdx.x;
    const int i   = blockIdx.x;
    const int b   = blockIdx.y;

    // --- stage weight slice for this i: weight[(i*8 + d)*128 + c] ---
    // element e = tid*4 + k  ->  d = e/128 = tid>>5,  c = e%128   (threads 0..255)
    const int wd = tid >> 5;
    const int wc = (tid * 4) & (C_ - 1);
    if (tid < 256) {
        const float4 wv = *reinterpret_cast<const float4*>(
            weight + (size_t)i * (D_ * C_) + tid * 4);
        w_lds[wc + 0][wd] = wv.x;
        w_lds[wc + 1][wd] = wv.y;
        w_lds[wc + 2][wd] = wv.z;
        w_lds[wc + 3][wd] = wv.w;
    }
    __syncthreads();

    // --- per-row L2 norm + max-norm scale (threads 0..127; 16 lanes per d) ---
    if (tid < 128) {
        const int d = tid >> 4;
        const int g = tid & 15;
        float s = 0.f;
        #pragma unroll
        for (int k = 0; k < 8; ++k) {
            const float v = w_lds[g * 8 + k][d];
            s = fmaf(v, v, s);
        }
        s += __shfl_xor(s, 1);
        s += __shfl_xor(s, 2);
        s += __shfl_xor(s, 4);
        s += __shfl_xor(s, 8);
        if (g == 0) {
            const float norm = sqrtf(s);
            s_scale[d] = fminf(1.0f, MAX_NORM_ / fmaxf(norm, 1e-12f));
        }
    }
    __syncthreads();
    if (tid < 256) {
        const float sc = s_scale[wd];
        w_lds[wc + 0][wd] *= sc;
        w_lds[wc + 1][wd] *= sc;
        w_lds[wc + 2][wd] *= sc;
        w_lds[wc + 3][wd] *= sc;
    }
    __syncthreads();

    // --- main loop: acc[d] += x[b,i,c,t] * w[c][d] ---
    const float* xp = x + ((size_t)(b * I_ + i) * C_) * T_ + tid * 4;

    f32x4 acc[D_];
    #pragma unroll
    for (int d = 0; d < D_; ++d) acc[d] = (f32x4)(0.f);

    #pragma unroll 8
    for (int c = 0; c < C_; ++c) {
        const f32x4 xv = __builtin_nontemporal_load(
            reinterpret_cast<const f32x4*>(xp + (size_t)c * T_));
        #pragma unroll
        for (int d = 0; d < D_; ++d) {
            const float w = w_lds[c][d];   // same-address broadcast
            acc[d].x = fmaf(xv.x, w, acc[d].x);
            acc[d].y = fmaf(xv.y, w, acc[d].y);
            acc[d].z = fmaf(xv.z, w, acc[d].z);
            acc[d].w = fmaf(xv.w, w, acc[d].w);
        }
    }

    // --- store: out[b, i*8+d, 0, t] ---
    float* op = out + ((size_t)(b * OUT_CH_ + i * D_)) * T_ + tid * 4;
    #pragma unroll
    for (int d = 0; d < D_; ++d) {
        __builtin_nontemporal_store(acc[d],
            reinterpret_cast<f32x4*>(op + (size_t)d * T_));
    }
}

extern "C" void kernel_launch(void* const* d_in, const int* in_sizes, int n_in,
                              void* d_out, int out_size, void* d_ws, size_t ws_size,
                              hipStream_t stream)
{
    const float* x = (const float*)d_in[0];
    const float* w = (const float*)d_in[1];
    float* out     = (float*)d_out;

    dim3 grid(I_, B_);   // (16, 32)
    DepthwiseSpatialConvROCm_kernel<<<grid, 512, 0, stream>>>(x, w, out);
}